// Round 17
// baseline (349.375 us; speedup 1.0000x reference)
//
#include <hip/hip_runtime.h>
#include <hip/hip_bf16.h>
#include <math.h>

// EntityAwareAttention on MI355X.
// K2 (ku2): fused W_hid prep + u2 entity projection (8 batches/block).
// K3 (kmain): FULLY FUSED, grid 2048 = one block per sentence b, 512 thr:
//     4x 32-token tiles processed sequentially with reg-prefetch pipeline
//     (issue next tile's HBM loads in two rounds around the K-loop),
//     split-K waves (wf[11]=44 VGPR, loaded ONCE per block),
//     per-tile (m,S) in LDS + zp partials in registers (static q indexing),
//     final log-sum-exp combine in-block -> direct out write.
//     kcomb kernel and zp_ws/mS_ws round-trips eliminated.

#define B_    2048
#define L_    128
#define H2_   600
#define P_    50
#define A_    50
#define D700  700
#define KCN   22      // ceil(700/32) -> 704
#define KHALF 11
#define AP    64      // padded attention dim
#define MT    32      // tokens per tile
#define XP    712     // Xs row stride in bf16 elems (704 data + 8 pad)
#define NB    8       // batches per ku2 block

typedef __attribute__((ext_vector_type(8))) short short8;
typedef __attribute__((ext_vector_type(4))) float f32x4;

__device__ __forceinline__ unsigned short f2bf(float f) {
  unsigned u = __float_as_uint(f);
  u += 0x7fffu + ((u >> 16) & 1u);   // round-to-nearest-even
  return (unsigned short)(u >> 16);
}
__device__ __forceinline__ unsigned cvtpk(float a, float b) {
  unsigned r;
  asm("v_cvt_pk_bf16_f32 %0, %1, %2" : "=v"(r) : "v"(a), "v"(b));
  return r;
}
__device__ __forceinline__ float bf2f(unsigned short s) {
  return __uint_as_float(((unsigned)s) << 16);
}

// ------- K2: fused W_hid prep + u2[b][0..63], 8 batches per block ---------
__global__ __launch_bounds__(512, 4) void ku2(const float* __restrict__ hidden,
                                              const int* __restrict__ e1,
                                              const int* __restrict__ e2,
                                              const float* __restrict__ Went,
                                              const float* __restrict__ lt,
                                              const float* __restrict__ Wh,
                                              unsigned short* __restrict__ Wt,
                                              float* __restrict__ u2ws) {
  __shared__ __align__(16) float E[NB][2400];   // 76,800 B
  __shared__ float dots[NB][2][3];
  __shared__ float aw[NB][2][3];
  int tid = threadIdx.x;
  int b0 = blockIdx.x * NB;

  {
    int gidx = blockIdx.x * 512 + tid;
    if (gidx < KCN * 2048) {
      int kc = gidx >> 11, r = gidx & 2047, a = r >> 5, kk = r & 31;
      int d = kc * 32 + kk;
      float v = (a < A_ && d < D700) ? Wh[a * D700 + d] : 0.f;
      Wt[gidx] = f2bf(v);
    }
  }

  for (int idx = tid; idx < NB * 2 * 150; idx += 512) {
    int i = idx / 300, r = idx - i * 300, e = r / 150, g = r - e * 150;
    int bb = b0 + i;
    int l = e ? e2[bb] : e1[bb];
    float4 f = *(const float4*)(hidden + ((size_t)bb * L_ + l) * H2_ + g * 4);
    *(float4*)(&E[i][e * 1200 + g * 4]) = f;
  }
  __syncthreads();

  int w = tid >> 6, lane = tid & 63;
  #pragma unroll
  for (int j = 0; j < 6; ++j) {
    int i = w, e = (j >= 3) ? 1 : 0, t = j % 3;
    float p = 0.f;
    for (int d = lane; d < 600; d += 64) p += E[i][e * 1200 + d] * lt[t * 600 + d];
    #pragma unroll
    for (int mask = 1; mask <= 32; mask <<= 1) p += __shfl_xor(p, mask);
    if (lane == 0) dots[i][e][t] = p;
  }
  __syncthreads();
  if (tid < NB * 6) {
    int t = tid % 3, e = (tid / 3) & 1, i = tid / 6;
    float d0 = dots[i][e][0], d1 = dots[i][e][1], d2 = dots[i][e][2];
    float m = fmaxf(d0, fmaxf(d1, d2));
    float x0 = expf(d0 - m), x1 = expf(d1 - m), x2 = expf(d2 - m);
    float Z = x0 + x1 + x2;
    aw[i][e][t] = ((t == 0) ? x0 : (t == 1) ? x1 : x2) / Z;
  }
  __syncthreads();
  for (int idx = tid; idx < NB * 2 * 600; idx += 512) {
    int i = idx / 1200, r = idx - i * 1200, e = r / 600, d = r - e * 600;
    float v = aw[i][e][0] * lt[d] + aw[i][e][1] * lt[600 + d] + aw[i][e][2] * lt[1200 + d];
    E[i][e * 1200 + 600 + d] = v;
  }
  __syncthreads();
  for (int a = w; a < A_; a += 8) {
    float acc[NB] = {0.f, 0.f, 0.f, 0.f, 0.f, 0.f, 0.f, 0.f};
    for (int d0 = lane * 4; d0 < 2400; d0 += 256) {
      float4 wv = *(const float4*)(Went + a * 2400 + d0);
      #pragma unroll
      for (int i = 0; i < NB; ++i) {
        float4 ev = *(const float4*)(&E[i][d0]);
        acc[i] += ev.x * wv.x + ev.y * wv.y + ev.z * wv.z + ev.w * wv.w;
      }
    }
    #pragma unroll
    for (int i = 0; i < NB; ++i) {
      float p = acc[i];
      #pragma unroll
      for (int mask = 1; mask <= 32; mask <<= 1) p += __shfl_xor(p, mask);
      if (lane == 0) u2ws[(b0 + i) * AP + a] = p;
    }
  }
  for (int idx = tid; idx < NB * (AP - A_); idx += 512) {
    u2ws[(b0 + idx / (AP - A_)) * AP + A_ + idx % (AP - A_)] = 0.f;
  }
}

// ---- K3: fully fused main kernel (one block per b, 4-tile pipeline) ------
__global__ __launch_bounds__(512, 4) void kmain(
    const float* __restrict__ hidden, const float* __restrict__ pos1,
    const float* __restrict__ pos2, const float* __restrict__ vvec,
    const unsigned short* __restrict__ Wt, const float* __restrict__ u2ws,
    float* __restrict__ out) {
  __shared__ __align__(16) unsigned short Xs[MT * XP];   // 45,568 B
  __shared__ __align__(16) float pacc[4][64][8];         //  8,192 B
  __shared__ float scores4[4][MT];
  __shared__ float es_s[MT];
  __shared__ float msl[4][2];

  int tid = threadIdx.x;
  int b = blockIdx.x;
  int w = tid >> 6, lane = tid & 63;
  int acol = lane & 15, kgrp = lane >> 4;
  int at = w & 3, kc0 = (w >> 2) * KHALF;
  int aidx = at * 16 + acol;
  int t = tid >> 4, c0 = tid & 15;
  bool h10 = (c0 < 6);
  bool hq = (tid < 288);

  // ---- per-block persistent state
  float u2v = u2ws[b * AP + aidx];
  float va = (aidx < A_) ? vvec[aidx] : 0.f;
  const unsigned short* wbase = Wt + aidx * 32 + kgrp * 8;
  const float* hb = hidden + (size_t)b * L_ * H2_;
  const float* p1b = pos1 + (size_t)b * L_ * P_;
  const float* p2b = pos2 + (size_t)b * L_ * P_;

  float4 zacc[4];          // zp partial per tile (tid<150), static q index
  #pragma unroll
  for (int q = 0; q < 4; ++q) { zacc[q].x = 0.f; zacc[q].y = 0.f; zacc[q].z = 0.f; zacc[q].w = 0.f; }

  // ---- prologue: stage tile 0 (deep queue), then wf
  {
    const float* rowp = hb + (size_t)t * H2_;
    float4 f[9], f9 = {0.f, 0.f, 0.f, 0.f};
    #pragma unroll
    for (int j = 0; j < 9; ++j) f[j] = *(const float4*)(rowp + (c0 + 16 * j) * 4);
    if (h10) f9 = *(const float4*)(rowp + (c0 + 144) * 4);
    float2 q1a = *(const float2*)(p1b + tid * 2);
    float2 q2a = *(const float2*)(p2b + tid * 2);
    float2 q1b = {0.f, 0.f}, q2b = {0.f, 0.f};
    if (hq) {
      q1b = *(const float2*)(p1b + (tid + 512) * 2);
      q2b = *(const float2*)(p2b + (tid + 512) * 2);
    }
    #pragma unroll
    for (int j = 0; j < 9; ++j) {
      uint2 wv2; wv2.x = cvtpk(f[j].x, f[j].y); wv2.y = cvtpk(f[j].z, f[j].w);
      *(uint2*)(&Xs[t * XP + (c0 + 16 * j) * 4]) = wv2;
    }
    if (h10) {
      uint2 wv2; wv2.x = cvtpk(f9.x, f9.y); wv2.y = cvtpk(f9.z, f9.w);
      *(uint2*)(&Xs[t * XP + (c0 + 144) * 4]) = wv2;
    }
    {
      int t1 = tid / 25, g = tid - t1 * 25;
      *(unsigned*)(&Xs[t1 * XP + 600 + g * 2]) = cvtpk(q1a.x, q1a.y);
      *(unsigned*)(&Xs[t1 * XP + 650 + g * 2]) = cvtpk(q2a.x, q2a.y);
    }
    if (hq) {
      int idx = tid + 512;
      int t1 = idx / 25, g = idx - t1 * 25;
      *(unsigned*)(&Xs[t1 * XP + 600 + g * 2]) = cvtpk(q1b.x, q1b.y);
      *(unsigned*)(&Xs[t1 * XP + 650 + g * 2]) = cvtpk(q2b.x, q2b.y);
    }
    if (tid < MT) {
      uint2 zz; zz.x = 0u; zz.y = 0u;
      *(uint2*)(&Xs[tid * XP + 700]) = zz;
    }
  }
  short8 wf[KHALF];
  #pragma unroll
  for (int kc = 0; kc < KHALF; ++kc)
    wf[kc] = *(const short8*)(wbase + (kc0 + kc) * 2048);
  __syncthreads();

  // ---- 4-tile loop (fully unrolled; q compile-time)
  #pragma unroll
  for (int q = 0; q < 4; ++q) {
    bool hasnext = (q < 3);
    const float* rowpn = hb + ((size_t)((q + 1) * MT) + t) * H2_;

    // -- round A: issue next tile hidden f4 cols j=0..4
    float4 nf[9]; float4 nf9 = {0.f, 0.f, 0.f, 0.f};
    float2 nq1a = {0.f, 0.f}, nq2a = {0.f, 0.f}, nq1b = {0.f, 0.f}, nq2b = {0.f, 0.f};
    if (hasnext) {
      #pragma unroll
      for (int j = 0; j < 5; ++j) nf[j] = *(const float4*)(rowpn + (c0 + 16 * j) * 4);
    }

    // -- K-loop: two independent 11-MFMA chains (token halves)
    f32x4 acc0 = {0.f, 0.f, 0.f, 0.f}, acc1 = {0.f, 0.f, 0.f, 0.f};
    #pragma unroll
    for (int kc = 0; kc < KHALF; ++kc) {
      int ke = (kc0 + kc) * 32 + kgrp * 8;
      short8 a0 = *(const short8*)(&Xs[acol * XP + ke]);
      short8 a1 = *(const short8*)(&Xs[(16 + acol) * XP + ke]);
      acc0 = __builtin_amdgcn_mfma_f32_16x16x32_bf16(a0, wf[kc], acc0, 0, 0, 0);
      acc1 = __builtin_amdgcn_mfma_f32_16x16x32_bf16(a1, wf[kc], acc1, 0, 0, 0);
    }

    // -- round B: issue next tile hidden j=5..8 (+tail) and pos
    if (hasnext) {
      #pragma unroll
      for (int j = 5; j < 9; ++j) nf[j] = *(const float4*)(rowpn + (c0 + 16 * j) * 4);
      if (h10) nf9 = *(const float4*)(rowpn + (c0 + 144) * 4);
      const float* p1n = p1b + (q + 1) * MT * P_;
      const float* p2n = p2b + (q + 1) * MT * P_;
      nq1a = *(const float2*)(p1n + tid * 2);
      nq2a = *(const float2*)(p2n + tid * 2);
      if (hq) {
        nq1b = *(const float2*)(p1n + (tid + 512) * 2);
        nq2b = *(const float2*)(p2n + (tid + 512) * 2);
      }
    }

    // -- combine K-halves + scores
    if (w >= 4) {
      float4 pv0 = {acc0[0], acc0[1], acc0[2], acc0[3]};
      float4 pv1 = {acc1[0], acc1[1], acc1[2], acc1[3]};
      *(float4*)(&pacc[w - 4][lane][0]) = pv0;
      *(float4*)(&pacc[w - 4][lane][4]) = pv1;
    }
    __syncthreads();   // B1
    if (w < 4) {
      float4 pv0 = *(const float4*)(&pacc[w][lane][0]);
      float4 pv1 = *(const float4*)(&pacc[w][lane][4]);
      float s0[4], s1[4];
      s0[0] = va * tanhf(acc0[0] + pv0.x + u2v);
      s0[1] = va * tanhf(acc0[1] + pv0.y + u2v);
      s0[2] = va * tanhf(acc0[2] + pv0.z + u2v);
      s0[3] = va * tanhf(acc0[3] + pv0.w + u2v);
      s1[0] = va * tanhf(acc1[0] + pv1.x + u2v);
      s1[1] = va * tanhf(acc1[1] + pv1.y + u2v);
      s1[2] = va * tanhf(acc1[2] + pv1.z + u2v);
      s1[3] = va * tanhf(acc1[3] + pv1.w + u2v);
      #pragma unroll
      for (int mask = 1; mask < 16; mask <<= 1) {
        #pragma unroll
        for (int r = 0; r < 4; ++r) {
          s0[r] += __shfl_xor(s0[r], mask);
          s1[r] += __shfl_xor(s1[r], mask);
        }
      }
      if (acol == 0) {
        #pragma unroll
        for (int r = 0; r < 4; ++r) {
          scores4[w][kgrp * 4 + r] = s0[r];
          scores4[w][16 + kgrp * 4 + r] = s1[r];
        }
      }
    }
    __syncthreads();   // B2

    // -- per-tile softmax (wave 0): m_q, S_q, es
    if (tid < 64) {
      float s = (tid < MT)
                    ? (scores4[0][tid] + scores4[1][tid] + scores4[2][tid] + scores4[3][tid])
                    : -3.402823466e38f;
      float m = s;
      #pragma unroll
      for (int mask = 1; mask <= 32; mask <<= 1) m = fmaxf(m, __shfl_xor(m, mask));
      float e = (tid < MT) ? expf(s - m) : 0.f;
      float S = e;
      #pragma unroll
      for (int mask = 1; mask <= 32; mask <<= 1) S += __shfl_xor(S, mask);
      if (tid < MT) es_s[tid] = e;
      if (tid == 0) { msl[q][0] = m; msl[q][1] = S; }
    }
    __syncthreads();   // B3

    // -- z-partial into registers (static q index)
    if (tid < 150) {
      float z0 = 0.f, z1 = 0.f, z2 = 0.f, z3 = 0.f;
      #pragma unroll
      for (int r = 0; r < MT; ++r) {
        uint2 xv = *(const uint2*)(&Xs[r * XP + tid * 4]);
        float e = es_s[r];
        z0 += e * bf2f((unsigned short)(xv.x & 0xffff));
        z1 += e * bf2f((unsigned short)(xv.x >> 16));
        z2 += e * bf2f((unsigned short)(xv.y & 0xffff));
        z3 += e * bf2f((unsigned short)(xv.y >> 16));
      }
      zacc[q].x = z0; zacc[q].y = z1; zacc[q].z = z2; zacc[q].w = z3;
    }
    __syncthreads();   // B4: Xs consumed, safe to overwrite

    // -- cvt+write next tile into Xs
    if (hasnext) {
      #pragma unroll
      for (int j = 0; j < 9; ++j) {
        uint2 wv2; wv2.x = cvtpk(nf[j].x, nf[j].y); wv2.y = cvtpk(nf[j].z, nf[j].w);
        *(uint2*)(&Xs[t * XP + (c0 + 16 * j) * 4]) = wv2;
      }
      if (h10) {
        uint2 wv2; wv2.x = cvtpk(nf9.x, nf9.y); wv2.y = cvtpk(nf9.z, nf9.w);
        *(uint2*)(&Xs[t * XP + (c0 + 144) * 4]) = wv2;
      }
      {
        int t1 = tid / 25, g = tid - t1 * 25;
        *(unsigned*)(&Xs[t1 * XP + 600 + g * 2]) = cvtpk(nq1a.x, nq1a.y);
        *(unsigned*)(&Xs[t1 * XP + 650 + g * 2]) = cvtpk(nq2a.x, nq2a.y);
      }
      if (hq) {
        int idx = tid + 512;
        int t1 = idx / 25, g = idx - t1 * 25;
        *(unsigned*)(&Xs[t1 * XP + 600 + g * 2]) = cvtpk(nq1b.x, nq1b.y);
        *(unsigned*)(&Xs[t1 * XP + 650 + g * 2]) = cvtpk(nq2b.x, nq2b.y);
      }
      __syncthreads();   // B5: Xs ready for next tile
    }
  }

  // ---- final: log-sum-exp combine across the 4 tiles, write out
  if (tid < 150) {
    float m0 = msl[0][0], m1 = msl[1][0], m2 = msl[2][0], m3 = msl[3][0];
    float M = fmaxf(fmaxf(m0, m1), fmaxf(m2, m3));
    float c0_ = expf(m0 - M), c1_ = expf(m1 - M), c2_ = expf(m2 - M), c3_ = expf(m3 - M);
    float Z = msl[0][1] * c0_ + msl[1][1] * c1_ + msl[2][1] * c2_ + msl[3][1] * c3_;
    float inv = 1.f / Z;
    float4 r;
    r.x = (zacc[0].x * c0_ + zacc[1].x * c1_ + zacc[2].x * c2_ + zacc[3].x * c3_) * inv;
    r.y = (zacc[0].y * c0_ + zacc[1].y * c1_ + zacc[2].y * c2_ + zacc[3].y * c3_) * inv;
    r.z = (zacc[0].z * c0_ + zacc[1].z * c1_ + zacc[2].z * c2_ + zacc[3].z * c3_) * inv;
    r.w = (zacc[0].w * c0_ + zacc[1].w * c1_ + zacc[2].w * c2_ + zacc[3].w * c3_) * inv;
    *(float4*)(out + (size_t)b * 600 + tid * 4) = r;
  }
}

extern "C" void kernel_launch(void* const* d_in, const int* in_sizes, int n_in,
                              void* d_out, int out_size, void* d_ws, size_t ws_size,
                              hipStream_t stream) {
  const float* hidden = (const float*)d_in[0];
  const float* pos1   = (const float*)d_in[1];
  const float* pos2   = (const float*)d_in[2];
  const int*   e1     = (const int*)d_in[3];
  const int*   e2     = (const int*)d_in[4];
  const float* Whid   = (const float*)d_in[5];
  const float* Went   = (const float*)d_in[6];
  const float* lt     = (const float*)d_in[7];
  const float* vvec   = (const float*)d_in[8];
  float* out = (float*)d_out;

  char* ws = (char*)d_ws;
  unsigned short* Wt = (unsigned short*)ws;                       //  90,112 B (pad 98,304)
  float* u2ws  = (float*)(ws + 98304);                            // 524,288 B

  hipLaunchKernelGGL(ku2, dim3(B_ / NB), dim3(512), 0, stream, hidden, e1, e2, Went, lt,
                     Whid, Wt, u2ws);
  hipLaunchKernelGGL(kmain, dim3(B_), dim3(512), 0, stream, hidden, pos1, pos2, vvec,
                     Wt, u2ws, out);
}

// Round 18
// 223.856 us; speedup vs baseline: 1.5607x; 1.5607x over previous
//
#include <hip/hip_runtime.h>
#include <hip/hip_bf16.h>
#include <math.h>

// EntityAwareAttention on MI355X.  (R14 best configuration, restored)
// K2 (ku2): FUSED W_hid prep + u2 entity projection.
//     - kwprep work folded in (45056 elems over grid 256x512)
//     - 8 batches/block (W_ent L2 traffic 491->123 MB), E[8][2400] fp32 LDS
// K3 (kmain): 512 thr, split-K 8 waves, one 32-token tile per block,
//     deep-queue staging -> cvt_pk -> bf16 Xs, two 11-MFMA chains,
//     per-32-token softmax + z-partial.
// K4 (kcomb): combine 4 partials per b (log-sum-exp), write z.

#define B_    2048
#define L_    128
#define H2_   600
#define P_    50
#define A_    50
#define D700  700
#define KCN   22      // ceil(700/32) -> 704
#define KHALF 11
#define AP    64      // padded attention dim
#define MT    32      // tokens per tile
#define XP    712     // Xs row stride in bf16 elems (704 data + 8 pad)
#define NB    8       // batches per ku2 block

typedef __attribute__((ext_vector_type(8))) short short8;
typedef __attribute__((ext_vector_type(4))) float f32x4;

__device__ __forceinline__ unsigned short f2bf(float f) {
  unsigned u = __float_as_uint(f);
  u += 0x7fffu + ((u >> 16) & 1u);   // round-to-nearest-even
  return (unsigned short)(u >> 16);
}
__device__ __forceinline__ unsigned cvtpk(float a, float b) {
  unsigned r;
  asm("v_cvt_pk_bf16_f32 %0, %1, %2" : "=v"(r) : "v"(a), "v"(b));
  return r;
}
__device__ __forceinline__ float bf2f(unsigned short s) {
  return __uint_as_float(((unsigned)s) << 16);
}

// ------- K2: fused W_hid prep + u2[b][0..63], 8 batches per block ---------
__global__ __launch_bounds__(512, 4) void ku2(const float* __restrict__ hidden,
                                              const int* __restrict__ e1,
                                              const int* __restrict__ e2,
                                              const float* __restrict__ Went,
                                              const float* __restrict__ lt,
                                              const float* __restrict__ Wh,
                                              unsigned short* __restrict__ Wt,
                                              float* __restrict__ u2ws) {
  __shared__ __align__(16) float E[NB][2400];   // 76,800 B
  __shared__ float dots[NB][2][3];
  __shared__ float aw[NB][2][3];
  int tid = threadIdx.x;
  int b0 = blockIdx.x * NB;

  // ---- fused kwprep: Wt[kc][a][k] bf16 (45,056 elems over 131,072 threads)
  {
    int gidx = blockIdx.x * 512 + tid;
    if (gidx < KCN * 2048) {
      int kc = gidx >> 11, r = gidx & 2047, a = r >> 5, kk = r & 31;
      int d = kc * 32 + kk;
      float v = (a < A_ && d < D700) ? Wh[a * D700 + d] : 0.f;
      Wt[gidx] = f2bf(v);
    }
  }

  // ---- gather entity rows: NB x 2 x 150 float4
  for (int idx = tid; idx < NB * 2 * 150; idx += 512) {
    int i = idx / 300, r = idx - i * 300, e = r / 150, g = r - e * 150;
    int bb = b0 + i;
    int l = e ? e2[bb] : e1[bb];
    float4 f = *(const float4*)(hidden + ((size_t)bb * L_ + l) * H2_ + g * 4);
    *(float4*)(&E[i][e * 1200 + g * 4]) = f;
  }
  __syncthreads();

  int w = tid >> 6, lane = tid & 63;
  // ---- 48 dot products: wave w -> i=w, 6 tasks (e = j>=3, t = j%3)
  #pragma unroll
  for (int j = 0; j < 6; ++j) {
    int i = w, e = (j >= 3) ? 1 : 0, t = j % 3;
    float p = 0.f;
    for (int d = lane; d < 600; d += 64) p += E[i][e * 1200 + d] * lt[t * 600 + d];
    #pragma unroll
    for (int mask = 1; mask <= 32; mask <<= 1) p += __shfl_xor(p, mask);
    if (lane == 0) dots[i][e][t] = p;
  }
  __syncthreads();
  if (tid < NB * 6) {
    int t = tid % 3, e = (tid / 3) & 1, i = tid / 6;
    float d0 = dots[i][e][0], d1 = dots[i][e][1], d2 = dots[i][e][2];
    float m = fmaxf(d0, fmaxf(d1, d2));
    float x0 = expf(d0 - m), x1 = expf(d1 - m), x2 = expf(d2 - m);
    float Z = x0 + x1 + x2;
    aw[i][e][t] = ((t == 0) ? x0 : (t == 1) ? x1 : x2) / Z;
  }
  __syncthreads();
  // ---- e_type fill
  for (int idx = tid; idx < NB * 2 * 600; idx += 512) {
    int i = idx / 1200, r = idx - i * 1200, e = r / 600, d = r - e * 600;
    float v = aw[i][e][0] * lt[d] + aw[i][e][1] * lt[600 + d] + aw[i][e][2] * lt[1200 + d];
    E[i][e * 1200 + 600 + d] = v;
  }
  __syncthreads();
  // ---- u2: wave w handles a = w, w+8, ... ; acc over 8 batches
  for (int a = w; a < A_; a += 8) {
    float acc[NB] = {0.f, 0.f, 0.f, 0.f, 0.f, 0.f, 0.f, 0.f};
    for (int d0 = lane * 4; d0 < 2400; d0 += 256) {
      float4 wv = *(const float4*)(Went + a * 2400 + d0);
      #pragma unroll
      for (int i = 0; i < NB; ++i) {
        float4 ev = *(const float4*)(&E[i][d0]);
        acc[i] += ev.x * wv.x + ev.y * wv.y + ev.z * wv.z + ev.w * wv.w;
      }
    }
    #pragma unroll
    for (int i = 0; i < NB; ++i) {
      float p = acc[i];
      #pragma unroll
      for (int mask = 1; mask <= 32; mask <<= 1) p += __shfl_xor(p, mask);
      if (lane == 0) u2ws[(b0 + i) * AP + a] = p;
    }
  }
  // ---- zero pad a = 50..63
  for (int idx = tid; idx < NB * (AP - A_); idx += 512) {
    u2ws[(b0 + idx / (AP - A_)) * AP + A_ + idx % (AP - A_)] = 0.f;
  }
}

// ------ K3: main fused kernel (512 thr, split-K, 32-token tile) -----------
__global__ __launch_bounds__(512, 4) void kmain(
    const float* __restrict__ hidden, const float* __restrict__ pos1,
    const float* __restrict__ pos2, const float* __restrict__ vvec,
    const unsigned short* __restrict__ Wt, const float* __restrict__ u2ws,
    float* __restrict__ zp_ws, float* __restrict__ mS_ws) {
  __shared__ __align__(16) unsigned short Xs[MT * XP];   // 45,568 B
  __shared__ __align__(16) float pacc[4][64][8];         //  8,192 B
  __shared__ float scores4[4][MT];
  __shared__ float es_s[MT];
  __shared__ float u2s[AP];
  __shared__ float vs[AP];

  int tid = threadIdx.x;
  int T = blockIdx.x;
  int b = T >> 2, tok0 = (T & 3) * MT;
  int w = tid >> 6, lane = tid & 63;
  int acol = lane & 15, kgrp = lane >> 4;

  // ======== PHASE 1: issue ALL tile global loads (deep VMEM queue) ========
  int t = tid >> 4, c0 = tid & 15;          // hidden row t (0..31), f4 col c0+16j
  const float* rowp = hidden + ((size_t)(b * L_ + tok0) + t) * H2_;
  float4 f[9];
  #pragma unroll
  for (int j = 0; j < 9; ++j) f[j] = *(const float4*)(rowp + (c0 + 16 * j) * 4);
  bool h10 = (c0 < 6);
  float4 f9;
  if (h10) f9 = *(const float4*)(rowp + (c0 + 144) * 4);

  const float* p1 = pos1 + (size_t)(b * L_ + tok0) * P_;
  const float* p2 = pos2 + (size_t)(b * L_ + tok0) * P_;
  float2 q1a = *(const float2*)(p1 + tid * 2);
  float2 q2a = *(const float2*)(p2 + tid * 2);
  bool hq = (tid < 288);                    // 800 float2 total: tid + (tid+512)
  float2 q1b, q2b;
  if (hq) {
    q1b = *(const float2*)(p1 + (tid + 512) * 2);
    q2b = *(const float2*)(p2 + (tid + 512) * 2);
  }
  float u2v = 0.f, vvv = 0.f;
  if (tid < AP) {
    u2v = u2ws[b * AP + tid];
    vvv = (tid < A_) ? vvec[tid] : 0.f;
  }

  // ======== PHASE 2: convert + LDS writes (waits tile loads only) ========
  #pragma unroll
  for (int j = 0; j < 9; ++j) {
    uint2 wv2; wv2.x = cvtpk(f[j].x, f[j].y); wv2.y = cvtpk(f[j].z, f[j].w);
    *(uint2*)(&Xs[t * XP + (c0 + 16 * j) * 4]) = wv2;
  }
  if (h10) {
    uint2 wv2; wv2.x = cvtpk(f9.x, f9.y); wv2.y = cvtpk(f9.z, f9.w);
    *(uint2*)(&Xs[t * XP + (c0 + 144) * 4]) = wv2;
  }
  {
    int t1 = tid / 25, g = tid - t1 * 25;
    *(unsigned*)(&Xs[t1 * XP + 600 + g * 2]) = cvtpk(q1a.x, q1a.y);
    *(unsigned*)(&Xs[t1 * XP + 650 + g * 2]) = cvtpk(q2a.x, q2a.y);
  }
  if (hq) {
    int idx = tid + 512;
    int t1 = idx / 25, g = idx - t1 * 25;
    *(unsigned*)(&Xs[t1 * XP + 600 + g * 2]) = cvtpk(q1b.x, q1b.y);
    *(unsigned*)(&Xs[t1 * XP + 650 + g * 2]) = cvtpk(q2b.x, q2b.y);
  }
  if (tid < MT) {           // zero pad cols 700..703
    uint2 zz; zz.x = 0u; zz.y = 0u;
    *(uint2*)(&Xs[tid * XP + 700]) = zz;
  }
  if (tid < AP) { u2s[tid] = u2v; vs[tid] = vvv; }

  // W half -> regs (L2-resident), issued after staging to cap reg pressure
  int at = w & 3;                 // a-tile
  int kc0 = (w >> 2) * KHALF;     // K-half start
  const unsigned short* wbase = Wt + (at * 16 + acol) * 32 + kgrp * 8;
  short8 wf[KHALF];
  #pragma unroll
  for (int kc = 0; kc < KHALF; ++kc)
    wf[kc] = *(const short8*)(wbase + (kc0 + kc) * 2048);
  __syncthreads();

  // ======== PHASE 3: two independent 11-MFMA chains (token halves) ========
  f32x4 acc0 = {0.f, 0.f, 0.f, 0.f}, acc1 = {0.f, 0.f, 0.f, 0.f};
  #pragma unroll
  for (int kc = 0; kc < KHALF; ++kc) {
    int ke = (kc0 + kc) * 32 + kgrp * 8;
    short8 a0 = *(const short8*)(&Xs[acol * XP + ke]);
    short8 a1 = *(const short8*)(&Xs[(16 + acol) * XP + ke]);
    acc0 = __builtin_amdgcn_mfma_f32_16x16x32_bf16(a0, wf[kc], acc0, 0, 0, 0);
    acc1 = __builtin_amdgcn_mfma_f32_16x16x32_bf16(a1, wf[kc], acc1, 0, 0, 0);
  }

  // ======== PHASE 4: combine K-halves + scores ========
  if (w >= 4) {
    float4 pv0 = {acc0[0], acc0[1], acc0[2], acc0[3]};
    float4 pv1 = {acc1[0], acc1[1], acc1[2], acc1[3]};
    *(float4*)(&pacc[w - 4][lane][0]) = pv0;
    *(float4*)(&pacc[w - 4][lane][4]) = pv1;
  }
  __syncthreads();
  if (w < 4) {
    float va = vs[w * 16 + acol];
    float u2a = u2s[w * 16 + acol];
    float4 pv0 = *(const float4*)(&pacc[w][lane][0]);
    float4 pv1 = *(const float4*)(&pacc[w][lane][4]);
    float s0[4], s1[4];
    s0[0] = va * tanhf(acc0[0] + pv0.x + u2a);
    s0[1] = va * tanhf(acc0[1] + pv0.y + u2a);
    s0[2] = va * tanhf(acc0[2] + pv0.z + u2a);
    s0[3] = va * tanhf(acc0[3] + pv0.w + u2a);
    s1[0] = va * tanhf(acc1[0] + pv1.x + u2a);
    s1[1] = va * tanhf(acc1[1] + pv1.y + u2a);
    s1[2] = va * tanhf(acc1[2] + pv1.z + u2a);
    s1[3] = va * tanhf(acc1[3] + pv1.w + u2a);
    #pragma unroll
    for (int mask = 1; mask < 16; mask <<= 1) {
      #pragma unroll
      for (int r = 0; r < 4; ++r) {
        s0[r] += __shfl_xor(s0[r], mask);
        s1[r] += __shfl_xor(s1[r], mask);
      }
    }
    if (acol == 0) {
      #pragma unroll
      for (int r = 0; r < 4; ++r) {
        scores4[w][kgrp * 4 + r] = s0[r];
        scores4[w][16 + kgrp * 4 + r] = s1[r];
      }
    }
  }
  __syncthreads();

  // ---- partial softmax over this block's 32 tokens (wave 0)
  if (tid < 64) {
    float s = (tid < MT)
                  ? (scores4[0][tid] + scores4[1][tid] + scores4[2][tid] + scores4[3][tid])
                  : -3.402823466e38f;
    float m = s;
    #pragma unroll
    for (int mask = 1; mask <= 32; mask <<= 1) m = fmaxf(m, __shfl_xor(m, mask));
    float e = (tid < MT) ? expf(s - m) : 0.f;
    float S = e;
    #pragma unroll
    for (int mask = 1; mask <= 32; mask <<= 1) S += __shfl_xor(S, mask);
    if (tid < MT) es_s[tid] = e;
    if (tid == 0) { mS_ws[T * 2] = m; mS_ws[T * 2 + 1] = S; }
  }
  __syncthreads();

  // ---- z-partial: zp[d] = sum_l exp(s_l - m) * hidden_bf16[l][d]
  if (tid < 150) {
    float z0 = 0.f, z1 = 0.f, z2 = 0.f, z3 = 0.f;
    #pragma unroll
    for (int r = 0; r < MT; ++r) {
      uint2 xv = *(const uint2*)(&Xs[r * XP + tid * 4]);   // 4 bf16
      float e = es_s[r];
      z0 += e * bf2f((unsigned short)(xv.x & 0xffff));
      z1 += e * bf2f((unsigned short)(xv.x >> 16));
      z2 += e * bf2f((unsigned short)(xv.y & 0xffff));
      z3 += e * bf2f((unsigned short)(xv.y >> 16));
    }
    float4 wv = {z0, z1, z2, z3};
    *(float4*)(zp_ws + (size_t)T * 600 + tid * 4) = wv;
  }
}

// ---------------- K4: combine 4 partials per b ----------------
__global__ __launch_bounds__(128) void kcomb(const float* __restrict__ zp_ws,
                                             const float* __restrict__ mS_ws,
                                             float* __restrict__ out) {
  int b = blockIdx.x, tid = threadIdx.x;
  float mq[4], Sq[4];
  #pragma unroll
  for (int qq = 0; qq < 4; ++qq) {
    mq[qq] = mS_ws[(b * 4 + qq) * 2];
    Sq[qq] = mS_ws[(b * 4 + qq) * 2 + 1];
  }
  float M = fmaxf(fmaxf(mq[0], mq[1]), fmaxf(mq[2], mq[3]));
  float c[4], Z = 0.f;
  #pragma unroll
  for (int qq = 0; qq < 4; ++qq) { c[qq] = expf(mq[qq] - M); Z += Sq[qq] * c[qq]; }
  float inv = 1.f / Z;
  for (int d = tid; d < 600; d += 128) {
    float z = 0.f;
    #pragma unroll
    for (int qq = 0; qq < 4; ++qq) z += c[qq] * zp_ws[(size_t)(b * 4 + qq) * 600 + d];
    out[b * 600 + d] = z * inv;
  }
}

extern "C" void kernel_launch(void* const* d_in, const int* in_sizes, int n_in,
                              void* d_out, int out_size, void* d_ws, size_t ws_size,
                              hipStream_t stream) {
  const float* hidden = (const float*)d_in[0];
  const float* pos1   = (const float*)d_in[1];
  const float* pos2   = (const float*)d_in[2];
  const int*   e1     = (const int*)d_in[3];
  const int*   e2     = (const int*)d_in[4];
  const float* Whid   = (const float*)d_in[5];
  const float* Went   = (const float*)d_in[6];
  const float* lt     = (const float*)d_in[7];
  const float* vvec   = (const float*)d_in[8];
  float* out = (float*)d_out;

  char* ws = (char*)d_ws;
  unsigned short* Wt = (unsigned short*)ws;                       //  90,112 B (pad 98,304)
  float* u2ws  = (float*)(ws + 98304);                            // 524,288 B
  float* mS_ws = (float*)(ws + 98304 + 524288);                   // 131,072 B
  float* zp_ws = (float*)(ws + 98304 + 524288 + 131072);          // 19,660,800 B

  hipLaunchKernelGGL(ku2, dim3(B_ / NB), dim3(512), 0, stream, hidden, e1, e2, Went, lt,
                     Whid, Wt, u2ws);
  hipLaunchKernelGGL(kmain, dim3(B_ * 4), dim3(512), 0, stream, hidden, pos1, pos2, vvec,
                     Wt, u2ws, zp_ws, mS_ws);
  hipLaunchKernelGGL(kcomb, dim3(B_), dim3(128), 0, stream, zp_ws, mS_ws, out);
}